// Round 7
// baseline (191.350 us; speedup 1.0000x reference)
//
#include <hip/hip_runtime.h>

// LocalSelfAttention2d  B=16,C=256,H=W=64,P=8,HEADS=8,D=32
// Round 7: latency attack (R6 showed stall-bound: Mfma 10%, VALU 18%, HBM 4%).
//  - K1/K2: explicit register double-buffer prefetch of global MFMA operands
//    (full-unroll parity buffers; loads for kt+1 issue before MFMAs of kt).
//  - K1: position[] staged in LDS (was 32 scattered global gathers/thread).
//  - K1: P overlays Q LDS (extra barrier after frag loads) -> LDS 67.6KB,
//    keeps 2 blocks/CU with POSL added.
// MFMA 16x16x32_f16 layouts (R4-R6 end-to-end verified):
//   A: row=l&15, k=(l>>4)*8+v ; B: col=l&15, same k ; D: col=l&15, row=(l>>4)*4+r.

typedef _Float16 f16x8 __attribute__((ext_vector_type(8)));
typedef float    f32x4 __attribute__((ext_vector_type(4)));
typedef unsigned short u16;
typedef unsigned long long u64;

#define SCALE 0.17677669529663687f  // 1/sqrt(32)
#define QK_S  40    // Q/K [64 pix][40 d]
#define VT_S  72    // V  [32 d][72 k]
#define PB_S  40    // P (overlays Q) [64 q][40 k]
#define LT_S  264   // T-kernel staging stride

__device__ __forceinline__ u16 f2hu(float f) {
    _Float16 h = (_Float16)f; return __builtin_bit_cast(u16, h);
}
__device__ __forceinline__ u64 pack4h(f32x4 v) {
    return (u64)f2hu(v[0]) | ((u64)f2hu(v[1]) << 16)
         | ((u64)f2hu(v[2]) << 32) | ((u64)f2hu(v[3]) << 48);
}

// ---------------- K0: weight fp32 -> fp16 ----------------
__global__ __launch_bounds__(512)
void conv_w(const float* __restrict__ wp, const float* __restrict__ wo,
            u16* __restrict__ w16, u16* __restrict__ wo16) {
    int idx = blockIdx.x * 512 + threadIdx.x;
    if (idx < 196608) w16[idx] = f2hu(wp[idx]);
    int j = idx - 196608;
    if (j >= 0 && j < 65536) wo16[j] = f2hu(wo[j]);
}

// ---------------- T: x [c][h][w] fp32 -> x_t [h][w][c] fp16 ----------------
__global__ __launch_bounds__(256)
void xt_transpose(const float* __restrict__ x, u16* __restrict__ xt) {
    __shared__ u16 Lt[64 * LT_S];   // swizzle c ^ (((w>>2)&7)<<3)
    const int tid = threadIdx.x;
    const int y = blockIdx.x, b = blockIdx.y;
    const float* xb = x + ((size_t)b * 256) * 4096 + y * 64;
    #pragma unroll
    for (int i = 0; i < 16; ++i) {
        int idx = tid + i * 256;
        int c = idx >> 4, w4 = (idx & 15) << 2;
        float4 v = *(const float4*)(xb + (size_t)c * 4096 + w4);
        float vv[4] = {v.x, v.y, v.z, v.w};
        #pragma unroll
        for (int j = 0; j < 4; ++j) {
            int w = w4 + j;
            Lt[w * LT_S + (c ^ (((w >> 2) & 7) << 3))] = f2hu(vv[j]);
        }
    }
    __syncthreads();
    u16* dst = xt + (((size_t)b * 64 + y) * 64) * 256;
    #pragma unroll
    for (int i = 0; i < 8; ++i) {
        int idx = tid + i * 256;
        int w = idx >> 5, c8 = (idx & 31) << 3;
        f16x8 v = *(const f16x8*)(&Lt[w * LT_S + (c8 ^ (((w >> 2) & 7) << 3))]);
        *(f16x8*)(dst + w * 256 + c8) = v;
    }
}

// ---------------- K1: QKV projection + windowed attention ----------------
__global__ __launch_bounds__(512, 4)
void lsa_qkv_attn_xt(const u16* __restrict__ xt, const u16* __restrict__ w16,
                     const float* __restrict__ position, u16* __restrict__ Ows)
{
    __shared__ u16 U[29696];        // 59392 B: Qb | Kb | Vt  (P overlays Qb)
    __shared__ float POSL[2048];    // 8192 B : position [8 heads][16][16]
    u16* Qb = U;                    // [4][64][40] = 10240
    u16* Kb = U + 10240;            // [4][64][40]
    u16* Vt = U + 20480;            // [4][32][72] = 9216

    const int tid = threadIdx.x;
    const int hq = blockIdx.x & 1, win = blockIdx.x >> 1, b = blockIdx.y;
    const int wy = win >> 3, wx = win & 7;
    const int w = tid >> 6, m = tid & 15, lg = (tid >> 4) & 3;

    // stage full position table (512 thr x float4 = 2048 f32)
    *(float4*)(&POSL[tid * 4]) = *(const float4*)(position + tid * 4);

    // ---- phase 2: QKV GEMM with register double-buffer prefetch
    f32x4 acc[3][4];
    int isv[3], hhv[3], d0v[3];
    const u16* arow[3];
    {
        const u16* xw = xt + ((size_t)b * 4096 + (wy * 8) * 64 + wx * 8) * 256;
        int pofs[4];
        #pragma unroll
        for (int nt = 0; nt < 4; ++nt) {
            int p = nt * 16 + m;
            pofs[nt] = ((p >> 3) * 64 + (p & 7)) * 256;
        }
        const f32x4 z = {0.f, 0.f, 0.f, 0.f};
        #pragma unroll
        for (int i = 0; i < 3; ++i) {
            #pragma unroll
            for (int nt = 0; nt < 4; ++nt) acc[i][nt] = z;
            int lr0 = (3 * w + i) * 16;           // local row: i_s*128 + hh*32 + d
            isv[i] = lr0 >> 7; hhv[i] = (lr0 >> 5) & 3; d0v[i] = lr0 & 31;
            int rowg = isv[i] * 256 + (hq * 4 + hhv[i]) * 32 + d0v[i];
            arow[i] = w16 + (size_t)(rowg + m) * 256 + lg * 8;
        }
        f16x8 af[2][3], bf[2][4];
        #pragma unroll
        for (int i = 0; i < 3; ++i) af[0][i] = *(const f16x8*)(arow[i]);
        #pragma unroll
        for (int nt = 0; nt < 4; ++nt) bf[0][nt] = *(const f16x8*)(xw + pofs[nt] + lg * 8);
        #pragma unroll
        for (int kt = 0; kt < 8; ++kt) {
            const int cur = kt & 1, nxt = cur ^ 1;   // compile-time under full unroll
            if (kt < 7) {
                #pragma unroll
                for (int i = 0; i < 3; ++i)
                    af[nxt][i] = *(const f16x8*)(arow[i] + (kt + 1) * 32);
                #pragma unroll
                for (int nt = 0; nt < 4; ++nt)
                    bf[nxt][nt] = *(const f16x8*)(xw + pofs[nt] + (kt + 1) * 32 + lg * 8);
            }
            #pragma unroll
            for (int i = 0; i < 3; ++i)
                #pragma unroll
                for (int nt = 0; nt < 4; ++nt)
                    acc[i][nt] = __builtin_amdgcn_mfma_f32_16x16x32_f16(af[cur][i], bf[cur][nt], acc[i][nt], 0, 0, 0);
        }
    }

    // ---- phase 3: scatter Q/K/V to per-head LDS
    {
        #pragma unroll
        for (int i = 0; i < 3; ++i) {
            int i_s = isv[i], hh = hhv[i], d0 = d0v[i];
            #pragma unroll
            for (int nt = 0; nt < 4; ++nt) {
                int pix = nt * 16 + m;
                if (i_s < 2) {
                    u16* base = (i_s == 0) ? Qb : Kb;
                    *(u64*)(base + hh * 64 * QK_S + pix * QK_S + d0 + lg * 4) = pack4h(acc[i][nt]);
                } else {
                    #pragma unroll
                    for (int r = 0; r < 4; ++r)
                        Vt[hh * 32 * VT_S + (d0 + lg * 4 + r) * VT_S + pix] = f2hu(acc[i][nt][r]);
                }
            }
        }
    }
    __syncthreads();

    // ---- phase 4: attention; 2 waves per head (wave = (hh, q-half))
    {
        const int hh = w >> 1, qh = w & 1;
        const u16* Qh = Qb + hh * 64 * QK_S;
        const u16* Kh = Kb + hh * 64 * QK_S;
        const u16* Vh = Vt + hh * 32 * VT_S;
        u16* Ph = Qb + hh * 64 * PB_S;          // OVERLAY: P reuses Q region
        const float* posh = &POSL[(hq * 4 + hh) * 256];

        f16x8 kf[4], qf[2];
        #pragma unroll
        for (int kt = 0; kt < 4; ++kt)
            kf[kt] = *(const f16x8*)(Kh + (kt * 16 + m) * QK_S + lg * 8);
        #pragma unroll
        for (int qi = 0; qi < 2; ++qi)
            qf[qi] = *(const f16x8*)(Qh + ((2 * qh + qi) * 16 + m) * QK_S + lg * 8);
        __syncthreads();   // all Q-frag reads complete before P overlays Qb

        const f32x4 z = {0.f, 0.f, 0.f, 0.f};
        f32x4 st[4][2];
        #pragma unroll
        for (int kt = 0; kt < 4; ++kt)
            #pragma unroll
            for (int qi = 0; qi < 2; ++qi)
                st[kt][qi] = __builtin_amdgcn_mfma_f32_16x16x32_f16(kf[kt], qf[qi], z, 0, 0, 0);
        // lane holds S[q=(2qh+qi)*16+m][k=kt*16+lg*4+r]

        float inv[2];
        #pragma unroll
        for (int qi = 0; qi < 2; ++qi) {
            int q = (2 * qh + qi) * 16 + m, qy = q >> 3, qx = q & 7;
            float mx = -1e30f;
            #pragma unroll
            for (int kt = 0; kt < 4; ++kt)
                #pragma unroll
                for (int r = 0; r < 4; ++r) {
                    int k = kt * 16 + lg * 4 + r, ky = k >> 3, kx = k & 7;
                    float t = st[kt][qi][r] * SCALE + posh[(ky - qy + 8) * 16 + (kx - qx + 8)];
                    st[kt][qi][r] = t;
                    mx = fmaxf(mx, t);
                }
            mx = fmaxf(mx, __shfl_xor(mx, 16));
            mx = fmaxf(mx, __shfl_xor(mx, 32));
            float sum = 0.f;
            #pragma unroll
            for (int kt = 0; kt < 4; ++kt)
                #pragma unroll
                for (int r = 0; r < 4; ++r) {
                    float e = __expf(st[kt][qi][r] - mx);
                    st[kt][qi][r] = e; sum += e;
                }
            sum += __shfl_xor(sum, 16);
            sum += __shfl_xor(sum, 32);
            inv[qi] = 1.f / sum;
        }

        f32x4 ot[2][2];
        ot[0][0] = z; ot[0][1] = z; ot[1][0] = z; ot[1][1] = z;
        #pragma unroll
        for (int ks = 0; ks < 2; ++ks) {
            #pragma unroll
            for (int kh = 0; kh < 2; ++kh) {
                int kt = 2 * ks + kh;
                #pragma unroll
                for (int qi = 0; qi < 2; ++qi) {
                    f32x4 pv = st[kt][qi] * inv[qi];
                    *(u64*)(Ph + ((2 * qh + qi) * 16 + m) * PB_S + kh * 16 + lg * 4) = pack4h(pv);
                }
            }
            f16x8 pf[2], vf[2];
            #pragma unroll
            for (int qi = 0; qi < 2; ++qi)
                pf[qi] = *(const f16x8*)(Ph + ((2 * qh + qi) * 16 + m) * PB_S + lg * 8);
            #pragma unroll
            for (int dt = 0; dt < 2; ++dt)
                vf[dt] = *(const f16x8*)(Vh + (dt * 16 + m) * VT_S + ks * 32 + lg * 8);
            #pragma unroll
            for (int qi = 0; qi < 2; ++qi)
                #pragma unroll
                for (int dt = 0; dt < 2; ++dt)
                    ot[qi][dt] = __builtin_amdgcn_mfma_f32_16x16x32_f16(pf[qi], vf[dt], ot[qi][dt], 0, 0, 0);
        }

        // O -> Ows [bw][p=q][c] fp16; lane: c = dt*16+m, q-rows = lg*4+r
        const size_t obase = (size_t)(b * 64 + win) * 16384;
        #pragma unroll
        for (int qi = 0; qi < 2; ++qi)
            #pragma unroll
            for (int dt = 0; dt < 2; ++dt) {
                int c = (hq * 4 + hh) * 32 + dt * 16 + m;
                #pragma unroll
                for (int r = 0; r < 4; ++r) {
                    int q = (2 * qh + qi) * 16 + lg * 4 + r;
                    Ows[obase + q * 256 + c] = f2hu(ot[qi][dt][r]);
                }
            }
    }
}

// ---------------- K2: out-projection (zero LDS, prefetched) ----------------
__global__ __launch_bounds__(512, 4)
void lsa_outproj(const u16* __restrict__ Ows, const u16* __restrict__ wo16,
                 const float* __restrict__ b_out, float* __restrict__ out)
{
    const int tid = threadIdx.x;
    const int win = blockIdx.x, b = blockIdx.y;
    const int wy = win >> 3, wx = win & 7;
    const int w = tid >> 6, m = tid & 15, lg = (tid >> 4) & 3;
    const u16* Ow = Ows + (size_t)(b * 64 + win) * 16384;   // [64 p][256 c]

    const u16* wrow[2];
    const u16* orow[4];
    #pragma unroll
    for (int mt = 0; mt < 2; ++mt)
        wrow[mt] = wo16 + (size_t)(w * 32 + mt * 16 + m) * 256 + lg * 8;
    #pragma unroll
    for (int nt = 0; nt < 4; ++nt)
        orow[nt] = Ow + (nt * 16 + m) * 256 + lg * 8;

    f32x4 oa[2][4];
    {
        const f32x4 z = {0.f, 0.f, 0.f, 0.f};
        #pragma unroll
        for (int mt = 0; mt < 2; ++mt)
            #pragma unroll
            for (int nt = 0; nt < 4; ++nt) oa[mt][nt] = z;
    }
    f16x8 wf[2][2], of[2][4];
    #pragma unroll
    for (int mt = 0; mt < 2; ++mt) wf[0][mt] = *(const f16x8*)(wrow[mt]);
    #pragma unroll
    for (int nt = 0; nt < 4; ++nt) of[0][nt] = *(const f16x8*)(orow[nt]);
    #pragma unroll
    for (int kt = 0; kt < 8; ++kt) {
        const int cur = kt & 1, nxt = cur ^ 1;
        if (kt < 7) {
            #pragma unroll
            for (int mt = 0; mt < 2; ++mt)
                wf[nxt][mt] = *(const f16x8*)(wrow[mt] + (kt + 1) * 32);
            #pragma unroll
            for (int nt = 0; nt < 4; ++nt)
                of[nxt][nt] = *(const f16x8*)(orow[nt] + (kt + 1) * 32);
        }
        #pragma unroll
        for (int mt = 0; mt < 2; ++mt)
            #pragma unroll
            for (int nt = 0; nt < 4; ++nt)
                oa[mt][nt] = __builtin_amdgcn_mfma_f32_16x16x32_f16(wf[cur][mt], of[cur][nt], oa[mt][nt], 0, 0, 0);
    }
    float* ob = out + ((size_t)b * 256) * 4096 + (wy * 8) * 64 + wx * 8;
    #pragma unroll
    for (int mt = 0; mt < 2; ++mt)
        #pragma unroll
        for (int nt = 0; nt < 4; ++nt) {
            int p = nt * 16 + m, py = p >> 3, px = p & 7;
            #pragma unroll
            for (int r = 0; r < 4; ++r) {
                int oc = w * 32 + mt * 16 + lg * 4 + r;
                ob[(size_t)oc * 4096 + py * 64 + px] = oa[mt][nt][r] + b_out[oc];
            }
        }
}

extern "C" void kernel_launch(void* const* d_in, const int* in_sizes, int n_in,
                              void* d_out, int out_size, void* d_ws, size_t ws_size,
                              hipStream_t stream) {
    const float* x      = (const float*)d_in[0];
    const float* w_proj = (const float*)d_in[1];
    const float* pos    = (const float*)d_in[2];
    const float* w_out  = (const float*)d_in[3];
    const float* b_out  = (const float*)d_in[4];
    float* out = (float*)d_out;

    // d_ws: [0,32M) x_t fp16 [h][w][c] ; +32M w16 ; +384K wo16 ; then Ows
    // (ws_size >= 64.5MB verified empirically in R6 - the xt path ran)
    u16* xt   = (u16*)d_ws;
    u16* w16  = (u16*)((char*)d_ws + 33554432);
    u16* wo16 = (u16*)((char*)d_ws + 33554432 + 393216);
    u16* Ows  = (u16*)((char*)d_ws + 33554432 + 393216 + 131072);

    conv_w<<<512, 512, 0, stream>>>(w_proj, w_out, w16, wo16);
    xt_transpose<<<dim3(64, 16), 256, 0, stream>>>(x, xt);
    lsa_qkv_attn_xt<<<dim3(128, 16), 512, 0, stream>>>(xt, w16, pos, Ows);
    lsa_outproj<<<dim3(64, 16), 512, 0, stream>>>(Ows, wo16, b_out, out);
}

// Round 8
// 116.984 us; speedup vs baseline: 1.6357x; 1.6357x over previous
//
#include <hip/hip_runtime.h>

// LocalSelfAttention2d  B=16,C=256,H=W=64,P=8,HEADS=8,D=32
// Round 8: TA/L1-transaction attack. All MFMA operand panels are now
// LDS-staged with COALESCED contiguous loads (strided per-lane global frag
// loads fragmented ~16x at the TA; R6/R7 proved neither BW nor latency was
// the limiter). Weight/activation tensors are pre-laid-out so every staged
// chunk is contiguous:
//   K0: w16k[hq][kt][384][32], wo16k[kt][256][32]  (k-chunk-major fp16)
//   T : x_tw[b][win][pix][c] fp16 (window-major)
//   K1: 2-barrier staged GEMM (Wc[384][40] + Xw[64][264] padded LDS),
//       then attention phases 3/4 UNCHANGED from verified R7.
//   K2: 2-barrier staged GEMM (Woc[256][40] + Owt[64][264]).
// MFMA 16x16x32_f16 layouts (R4-R7 verified):
//   A: row=l&15, k=(l>>4)*8+v ; B: col=l&15, same k ; D: col=l&15, row=(l>>4)*4+r.

typedef _Float16 f16x8 __attribute__((ext_vector_type(8)));
typedef float    f32x4 __attribute__((ext_vector_type(4)));
typedef unsigned short u16;
typedef unsigned long long u64;

#define SCALE 0.17677669529663687f  // 1/sqrt(32)
#define QK_S  40    // Q/K [64 pix][40 d]
#define VT_S  72    // V  [32 d][72 k]
#define PB_S  40    // P (overlays Q) [64 q][40 k]
#define LT_S  264   // T-kernel staging stride
#define WC_S  40    // W-chunk LDS stride (80B rows: 2-way banks, 16B aligned)
#define XW_S  264   // x-window LDS stride (528B rows: 2-way banks, 16B aligned)

__device__ __forceinline__ u16 f2hu(float f) {
    _Float16 h = (_Float16)f; return __builtin_bit_cast(u16, h);
}
__device__ __forceinline__ u64 pack4h(f32x4 v) {
    return (u64)f2hu(v[0]) | ((u64)f2hu(v[1]) << 16)
         | ((u64)f2hu(v[2]) << 32) | ((u64)f2hu(v[3]) << 48);
}

// ---------------- K0: weights -> fp16, k-chunk-major ----------------
__global__ __launch_bounds__(512)
void conv_w(const float* __restrict__ wp, const float* __restrict__ wo,
            u16* __restrict__ w16k, u16* __restrict__ wo16k) {
    int idx = blockIdx.x * 512 + threadIdx.x;
    if (idx < 196608) {
        int hq = idx / 98304, o = idx - hq * 98304;
        int kt = o / 12288, o2 = o - kt * 12288;
        int lr = o2 >> 5, cc = o2 & 31;
        int s = lr >> 7, hh = (lr >> 5) & 3, d = lr & 31;
        w16k[idx] = f2hu(wp[(size_t)(s * 256 + (hq * 4 + hh) * 32 + d) * 256 + kt * 32 + cc]);
    }
    int j = idx - 196608;
    if (j >= 0 && j < 65536) {
        int kt = j >> 13, o2 = j & 8191;
        int row = o2 >> 5, cc = o2 & 31;
        wo16k[j] = f2hu(wo[(size_t)row * 256 + kt * 32 + cc]);
    }
}

// ---------------- T: x [c][h][w] fp32 -> x_tw [b][win][pix][c] fp16 ----------------
__global__ __launch_bounds__(256)
void xt_transpose(const float* __restrict__ x, u16* __restrict__ xtw) {
    __shared__ u16 Lt[64 * LT_S];   // swizzle c ^ (((w>>2)&7)<<3)
    const int tid = threadIdx.x;
    const int y = blockIdx.x, b = blockIdx.y;
    const int yq = y >> 3, py = y & 7;
    const float* xb = x + ((size_t)b * 256) * 4096 + y * 64;
    #pragma unroll
    for (int i = 0; i < 16; ++i) {
        int idx = tid + i * 256;
        int c = idx >> 4, w4 = (idx & 15) << 2;
        float4 v = *(const float4*)(xb + (size_t)c * 4096 + w4);
        float vv[4] = {v.x, v.y, v.z, v.w};
        #pragma unroll
        for (int j = 0; j < 4; ++j) {
            int w = w4 + j;
            Lt[w * LT_S + (c ^ (((w >> 2) & 7) << 3))] = f2hu(vv[j]);
        }
    }
    __syncthreads();
    u16* dst = xtw + (size_t)(b * 64 + yq * 8) * 16384;   // window-row base
    #pragma unroll
    for (int i = 0; i < 8; ++i) {
        int idx = tid + i * 256;
        int w = idx >> 5, c8 = (idx & 31) << 3;
        f16x8 v = *(const f16x8*)(&Lt[w * LT_S + (c8 ^ (((w >> 2) & 7) << 3))]);
        // pixel (y, w) -> window (yq, w>>3), pix (py*8 + (w&7))
        *(f16x8*)(dst + (w >> 3) * 16384 + (py * 8 + (w & 7)) * 256 + c8) = v;
    }
}

// ---------------- K1: QKV projection (LDS-staged) + windowed attention ----------------
__global__ __launch_bounds__(512, 4)
void lsa_qkv_attn_xt(const u16* __restrict__ xtw, const u16* __restrict__ w16k,
                     const float* __restrict__ position, u16* __restrict__ Ows)
{
    // U overlay: phase 1-2: Xw[64][264] (16896) | Wc[384][40] (15360) = 32256 u16
    //            phase 3-4: Qb 10240 | Kb 10240 | Vt 9216  (29696 u16)
    __shared__ u16 U[32256];        // 64512 B
    __shared__ float POSL[2048];    // 8192 B
    u16* XwL = U;                   // [64][264]
    u16* WcL = U + 16896;           // [384][40]
    u16* Qb  = U;                   // [4][64][40]
    u16* Kb  = U + 10240;
    u16* Vt  = U + 20480;           // [4][32][72]

    const int tid = threadIdx.x;
    const int hq = blockIdx.x & 1, win = blockIdx.x >> 1, b = blockIdx.y;
    const int w = tid >> 6, m = tid & 15, lg = (tid >> 4) & 3;

    // stage position table + x window (coalesced 16B, LDS padded rows)
    *(float4*)(&POSL[tid * 4]) = *(const float4*)(position + tid * 4);
    {
        const u16* xwin = xtw + (size_t)(b * 64 + win) * 16384;
        #pragma unroll
        for (int i = 0; i < 4; ++i) {
            int g = tid + i * 512;                  // 2048 16B-chunks
            *(f16x8*)(XwL + (g >> 5) * XW_S + (g & 31) * 8) = *(const f16x8*)(xwin + g * 8);
        }
    }

    // ---- phase 2: QKV GEMM, 2-barrier staged loop
    f32x4 acc[3][4];
    int isv[3], hhv[3], d0v[3], lr0v[3];
    {
        const f32x4 z = {0.f, 0.f, 0.f, 0.f};
        #pragma unroll
        for (int i = 0; i < 3; ++i) {
            #pragma unroll
            for (int nt = 0; nt < 4; ++nt) acc[i][nt] = z;
            int lr0 = (3 * w + i) * 16;           // local row: s*128 + hh*32 + d
            lr0v[i] = lr0;
            isv[i] = lr0 >> 7; hhv[i] = (lr0 >> 5) & 3; d0v[i] = lr0 & 31;
        }
        const u16* wbase = w16k + (size_t)hq * 98304;
        for (int kt = 0; kt < 8; ++kt) {
            if (kt) __syncthreads();              // protect Wc reuse
            const u16* wchunk = wbase + kt * 12288;
            #pragma unroll
            for (int i = 0; i < 3; ++i) {
                int g = tid + i * 512;            // 1536 16B-chunks
                *(f16x8*)(WcL + (g >> 2) * WC_S + (g & 3) * 8) = *(const f16x8*)(wchunk + g * 8);
            }
            __syncthreads();
            f16x8 af[3], bf[4];
            #pragma unroll
            for (int i = 0; i < 3; ++i)
                af[i] = *(const f16x8*)(WcL + (lr0v[i] + m) * WC_S + lg * 8);
            #pragma unroll
            for (int nt = 0; nt < 4; ++nt)
                bf[nt] = *(const f16x8*)(XwL + (nt * 16 + m) * XW_S + kt * 32 + lg * 8);
            #pragma unroll
            for (int i = 0; i < 3; ++i)
                #pragma unroll
                for (int nt = 0; nt < 4; ++nt)
                    acc[i][nt] = __builtin_amdgcn_mfma_f32_16x16x32_f16(af[i], bf[nt], acc[i][nt], 0, 0, 0);
        }
    }
    __syncthreads();   // all Xw/Wc reads done before Q/K/V overlays U

    // ---- phase 3: scatter Q/K/V to per-head LDS (unchanged, verified)
    {
        #pragma unroll
        for (int i = 0; i < 3; ++i) {
            int i_s = isv[i], hh = hhv[i], d0 = d0v[i];
            #pragma unroll
            for (int nt = 0; nt < 4; ++nt) {
                int pix = nt * 16 + m;
                if (i_s < 2) {
                    u16* base = (i_s == 0) ? Qb : Kb;
                    *(u64*)(base + hh * 64 * QK_S + pix * QK_S + d0 + lg * 4) = pack4h(acc[i][nt]);
                } else {
                    #pragma unroll
                    for (int r = 0; r < 4; ++r)
                        Vt[hh * 32 * VT_S + (d0 + lg * 4 + r) * VT_S + pix] = f2hu(acc[i][nt][r]);
                }
            }
        }
    }
    __syncthreads();

    // ---- phase 4: attention; 2 waves per head (unchanged, verified)
    {
        const int hh = w >> 1, qh = w & 1;
        const u16* Qh = Qb + hh * 64 * QK_S;
        const u16* Kh = Kb + hh * 64 * QK_S;
        const u16* Vh = Vt + hh * 32 * VT_S;
        u16* Ph = Qb + hh * 64 * PB_S;          // OVERLAY: P reuses Q region
        const float* posh = &POSL[(hq * 4 + hh) * 256];

        f16x8 kf[4], qf[2];
        #pragma unroll
        for (int kt = 0; kt < 4; ++kt)
            kf[kt] = *(const f16x8*)(Kh + (kt * 16 + m) * QK_S + lg * 8);
        #pragma unroll
        for (int qi = 0; qi < 2; ++qi)
            qf[qi] = *(const f16x8*)(Qh + ((2 * qh + qi) * 16 + m) * QK_S + lg * 8);
        __syncthreads();   // Q-frag reads complete before P overlays Qb

        const f32x4 z = {0.f, 0.f, 0.f, 0.f};
        f32x4 st[4][2];
        #pragma unroll
        for (int kt = 0; kt < 4; ++kt)
            #pragma unroll
            for (int qi = 0; qi < 2; ++qi)
                st[kt][qi] = __builtin_amdgcn_mfma_f32_16x16x32_f16(kf[kt], qf[qi], z, 0, 0, 0);
        // lane holds S[q=(2qh+qi)*16+m][k=kt*16+lg*4+r]

        float inv[2];
        #pragma unroll
        for (int qi = 0; qi < 2; ++qi) {
            int q = (2 * qh + qi) * 16 + m, qy = q >> 3, qx = q & 7;
            float mx = -1e30f;
            #pragma unroll
            for (int kt = 0; kt < 4; ++kt)
                #pragma unroll
                for (int r = 0; r < 4; ++r) {
                    int k = kt * 16 + lg * 4 + r, ky = k >> 3, kx = k & 7;
                    float t = st[kt][qi][r] * SCALE + posh[(ky - qy + 8) * 16 + (kx - qx + 8)];
                    st[kt][qi][r] = t;
                    mx = fmaxf(mx, t);
                }
            mx = fmaxf(mx, __shfl_xor(mx, 16));
            mx = fmaxf(mx, __shfl_xor(mx, 32));
            float sum = 0.f;
            #pragma unroll
            for (int kt = 0; kt < 4; ++kt)
                #pragma unroll
                for (int r = 0; r < 4; ++r) {
                    float e = __expf(st[kt][qi][r] - mx);
                    st[kt][qi][r] = e; sum += e;
                }
            sum += __shfl_xor(sum, 16);
            sum += __shfl_xor(sum, 32);
            inv[qi] = 1.f / sum;
        }

        f32x4 ot[2][2];
        ot[0][0] = z; ot[0][1] = z; ot[1][0] = z; ot[1][1] = z;
        #pragma unroll
        for (int ks = 0; ks < 2; ++ks) {
            #pragma unroll
            for (int kh = 0; kh < 2; ++kh) {
                int kt = 2 * ks + kh;
                #pragma unroll
                for (int qi = 0; qi < 2; ++qi) {
                    f32x4 pv = st[kt][qi] * inv[qi];
                    *(u64*)(Ph + ((2 * qh + qi) * 16 + m) * PB_S + kh * 16 + lg * 4) = pack4h(pv);
                }
            }
            f16x8 pf[2], vf[2];
            #pragma unroll
            for (int qi = 0; qi < 2; ++qi)
                pf[qi] = *(const f16x8*)(Ph + ((2 * qh + qi) * 16 + m) * PB_S + lg * 8);
            #pragma unroll
            for (int dt = 0; dt < 2; ++dt)
                vf[dt] = *(const f16x8*)(Vh + (dt * 16 + m) * VT_S + ks * 32 + lg * 8);
            #pragma unroll
            for (int qi = 0; qi < 2; ++qi)
                #pragma unroll
                for (int dt = 0; dt < 2; ++dt)
                    ot[qi][dt] = __builtin_amdgcn_mfma_f32_16x16x32_f16(pf[qi], vf[dt], ot[qi][dt], 0, 0, 0);
        }

        // O -> Ows [bw][p=q][c] fp16
        const size_t obase = (size_t)(b * 64 + win) * 16384;
        #pragma unroll
        for (int qi = 0; qi < 2; ++qi)
            #pragma unroll
            for (int dt = 0; dt < 2; ++dt) {
                int c = (hq * 4 + hh) * 32 + dt * 16 + m;
                #pragma unroll
                for (int r = 0; r < 4; ++r) {
                    int q = (2 * qh + qi) * 16 + lg * 4 + r;
                    Ows[obase + q * 256 + c] = f2hu(ot[qi][dt][r]);
                }
            }
    }
}

// ---------------- K2: out-projection (LDS-staged 2-barrier GEMM) ----------------
__global__ __launch_bounds__(512, 4)
void lsa_outproj(const u16* __restrict__ Ows, const u16* __restrict__ wo16k,
                 const float* __restrict__ b_out, float* __restrict__ out)
{
    __shared__ u16 Owt[64 * XW_S];    // 33792 B [64 pix][264]
    __shared__ u16 Woc[256 * WC_S];   // 20480 B [256 oc][40]

    const int tid = threadIdx.x;
    const int win = blockIdx.x, b = blockIdx.y;
    const int wy = win >> 3, wx = win & 7;
    const int w = tid >> 6, m = tid & 15, lg = (tid >> 4) & 3;

    {
        const u16* Ow = Ows + (size_t)(b * 64 + win) * 16384;
        #pragma unroll
        for (int i = 0; i < 4; ++i) {
            int g = tid + i * 512;
            *(f16x8*)(Owt + (g >> 5) * XW_S + (g & 31) * 8) = *(const f16x8*)(Ow + g * 8);
        }
    }

    f32x4 oa[2][4];
    {
        const f32x4 z = {0.f, 0.f, 0.f, 0.f};
        #pragma unroll
        for (int mt = 0; mt < 2; ++mt)
            #pragma unroll
            for (int nt = 0; nt < 4; ++nt) oa[mt][nt] = z;
    }
    for (int kt = 0; kt < 8; ++kt) {
        if (kt) __syncthreads();
        const u16* wchunk = wo16k + kt * 8192;
        #pragma unroll
        for (int i = 0; i < 2; ++i) {
            int g = tid + i * 512;                // 1024 16B-chunks
            *(f16x8*)(Woc + (g >> 2) * WC_S + (g & 3) * 8) = *(const f16x8*)(wchunk + g * 8);
        }
        __syncthreads();
        f16x8 wf[2], of[4];
        #pragma unroll
        for (int mt = 0; mt < 2; ++mt)
            wf[mt] = *(const f16x8*)(Woc + (w * 32 + mt * 16 + m) * WC_S + lg * 8);
        #pragma unroll
        for (int nt = 0; nt < 4; ++nt)
            of[nt] = *(const f16x8*)(Owt + (nt * 16 + m) * XW_S + kt * 32 + lg * 8);
        #pragma unroll
        for (int mt = 0; mt < 2; ++mt)
            #pragma unroll
            for (int nt = 0; nt < 4; ++nt)
                oa[mt][nt] = __builtin_amdgcn_mfma_f32_16x16x32_f16(wf[mt], of[nt], oa[mt][nt], 0, 0, 0);
    }
    float* ob = out + ((size_t)b * 256) * 4096 + (wy * 8) * 64 + wx * 8;
    #pragma unroll
    for (int mt = 0; mt < 2; ++mt)
        #pragma unroll
        for (int nt = 0; nt < 4; ++nt) {
            int p = nt * 16 + m, py = p >> 3, px = p & 7;
            #pragma unroll
            for (int r = 0; r < 4; ++r) {
                int oc = w * 32 + mt * 16 + lg * 4 + r;
                ob[(size_t)oc * 4096 + py * 64 + px] = oa[mt][nt][r] + b_out[oc];
            }
        }
}

extern "C" void kernel_launch(void* const* d_in, const int* in_sizes, int n_in,
                              void* d_out, int out_size, void* d_ws, size_t ws_size,
                              hipStream_t stream) {
    const float* x      = (const float*)d_in[0];
    const float* w_proj = (const float*)d_in[1];
    const float* pos    = (const float*)d_in[2];
    const float* w_out  = (const float*)d_in[3];
    const float* b_out  = (const float*)d_in[4];
    float* out = (float*)d_out;

    // d_ws: [0,32M) x_tw ; +32M w16k (384K) ; +393216 wo16k (128K) ; then Ows (32M)
    u16* xtw   = (u16*)d_ws;
    u16* w16k  = (u16*)((char*)d_ws + 33554432);
    u16* wo16k = (u16*)((char*)d_ws + 33554432 + 393216);
    u16* Ows   = (u16*)((char*)d_ws + 33554432 + 393216 + 131072);

    conv_w<<<512, 512, 0, stream>>>(w_proj, w_out, w16k, wo16k);
    xt_transpose<<<dim3(64, 16), 256, 0, stream>>>(x, xtw);
    lsa_qkv_attn_xt<<<dim3(128, 16), 512, 0, stream>>>(xtw, w16k, pos, Ows);
    lsa_outproj<<<dim3(64, 16), 512, 0, stream>>>(Ows, wo16k, b_out, out);
}